// Round 1
// baseline (1063.054 us; speedup 1.0000x reference)
//
#include <hip/hip_runtime.h>

// Problem constants (match reference)
static constexpr int H  = 1024, W = 1024, B = 8, C = 4, K = 3;
static constexpr int HW = H * W;
static constexpr int F  = (H / 2) * (W / 2);   // 262144 filled
static constexpr int U  = HW - F;              // 786432 unfilled
static constexpr int NP = B * C;               // 32 planes

// Kernel A: copy the even rows of coded into out (odd rows are 100% unfilled
// and will be fully written by fill_kernel; even rows' odd-j entries get
// overwritten by fill_kernel afterwards on the same stream).
__global__ void copy_even_rows_kernel(const float4* __restrict__ src,
                                      float4* __restrict__ dst) {
    const int per_plane = (H / 2) * (W / 4);   // 512 even rows * 256 float4
    int t = blockIdx.x * blockDim.x + threadIdx.x;
    if (t >= NP * per_plane) return;
    int p   = t / per_plane;
    int rem = t - p * per_plane;
    int r2  = rem >> 8;            // which even row (row = 2*r2)
    int c4  = rem & 255;           // float4 column
    int off = p * (HW / 4) + (r2 * 2) * (W / 4) + c4;
    dst[off] = src[off];
}

// Kernel B: one thread per unfilled pixel; loops over all 32 planes.
__global__ void fill_kernel(const float* __restrict__ coded,
                            const int*   __restrict__ idx,
                            const float* __restrict__ dist,
                            const int*   __restrict__ filled_idx,
                            const int*   __restrict__ unfilled_idx,
                            float* __restrict__ out) {
    int u = blockIdx.x * blockDim.x + threadIdx.x;
    if (u >= U) return;

    int i0 = idx[3 * u + 0];
    int i1 = idx[3 * u + 1];
    int i2 = idx[3 * u + 2];
    float w0 = 1.0f / dist[3 * u + 0];   // (1/d)^P with P=1.0
    float w1 = 1.0f / dist[3 * u + 1];
    float w2 = 1.0f / dist[3 * u + 2];
    float inv = 1.0f / (w0 + w1 + w2);
    w0 *= inv; w1 *= inv; w2 *= inv;

    int n0 = filled_idx[2 * i0] * W + filled_idx[2 * i0 + 1];
    int n1 = filled_idx[2 * i1] * W + filled_idx[2 * i1 + 1];
    int n2 = filled_idx[2 * i2] * W + filled_idx[2 * i2 + 1];
    int uf = unfilled_idx[2 * u] * W + unfilled_idx[2 * u + 1];

    #pragma unroll 4
    for (int p = 0; p < NP; ++p) {
        const float* pl = coded + (size_t)p * HW;
        out[(size_t)p * HW + uf] = w0 * pl[n0] + w1 * pl[n1] + w2 * pl[n2];
    }
}

extern "C" void kernel_launch(void* const* d_in, const int* in_sizes, int n_in,
                              void* d_out, int out_size, void* d_ws, size_t ws_size,
                              hipStream_t stream) {
    const float* coded        = (const float*)d_in[0];
    const int*   idx          = (const int*)d_in[1];
    const float* dist         = (const float*)d_in[2];
    const int*   filled_idx   = (const int*)d_in[3];
    const int*   unfilled_idx = (const int*)d_in[4];
    float*       out          = (float*)d_out;

    const int copy_threads = NP * (H / 2) * (W / 4);   // 4,194,304
    copy_even_rows_kernel<<<(copy_threads + 255) / 256, 256, 0, stream>>>(
        (const float4*)coded, (float4*)out);

    fill_kernel<<<(U + 255) / 256, 256, 0, stream>>>(
        coded, idx, dist, filled_idx, unfilled_idx, out);
}

// Round 2
// 142.270 us; speedup vs baseline: 7.4721x; 7.4721x over previous
//
#include <hip/hip_runtime.h>

// Problem constants (match reference)
static constexpr int H  = 1024, W = 1024, B = 8, C = 4, K = 3;
static constexpr int HW = H * W;
static constexpr int F  = (H / 2) * (W / 2);   // 262144 filled
static constexpr int U  = HW - F;              // 786432 unfilled
static constexpr int NP = B * C;               // 32 planes

// ---------------------------------------------------------------------------
// Fast path
// ---------------------------------------------------------------------------

// Kernel 1: for each filled pixel f (= r2*512 + c2, at image pos (2*r2, 2*c2)):
//   - copy the even-row float2 (filled val + neighbor) of all 32 planes to out
//     (fully coalesced read AND write; covers all even-row bytes)
//   - deposit the filled value of each plane into transposed table T[f][32]
//     (contiguous 128 B per f, coalesced float4 writes)
__global__ void build_T_copy_kernel(const float2* __restrict__ src2,
                                    float2* __restrict__ dst2,
                                    float4* __restrict__ T4) {
    int f = blockIdx.x * blockDim.x + threadIdx.x;
    if (f >= F) return;
    int r2 = f >> 9;          // 0..511
    int c2 = f & 511;
    int base = r2 * W + c2;   // float2 index within a plane (plane = HW/2 float2)
    float vals[NP];
    #pragma unroll
    for (int p = 0; p < NP; ++p) {
        float2 v = src2[(size_t)p * (HW / 2) + base];
        dst2[(size_t)p * (HW / 2) + base] = v;
        vals[p] = v.x;
    }
    float4* row = T4 + (size_t)f * (NP / 4);
    #pragma unroll
    for (int c = 0; c < NP / 4; ++c)
        row[c] = make_float4(vals[4*c], vals[4*c+1], vals[4*c+2], vals[4*c+3]);
}

// Kernel 2: one thread per unfilled pixel u. Gathers 3 contiguous 128 B rows
// of T, computes all 32 plane outputs, writes them (lane-coalesced per plane).
// uf is derived from the argwhere enumeration closed-form:
//   u block of 1536 = one even row (512 odd-col pixels) + one odd row (1024).
__global__ void fill_T_kernel(const int*   __restrict__ idx,
                              const float* __restrict__ dist,
                              const float4* __restrict__ T4,
                              float* __restrict__ out) {
    int u = blockIdx.x * blockDim.x + threadIdx.x;
    if (u >= U) return;

    int blk = u / 1536;
    int rem = u - blk * 1536;
    int row, col;
    if (rem < 512) { row = 2 * blk;     col = 2 * rem + 1; }
    else           { row = 2 * blk + 1; col = rem - 512;   }
    int uf = row * W + col;

    int i0 = idx[3*u + 0], i1 = idx[3*u + 1], i2 = idx[3*u + 2];
    float w0 = 1.0f / dist[3*u + 0];
    float w1 = 1.0f / dist[3*u + 1];
    float w2 = 1.0f / dist[3*u + 2];
    float inv = 1.0f / (w0 + w1 + w2);
    w0 *= inv; w1 *= inv; w2 *= inv;

    const float4* r0 = T4 + (size_t)i0 * (NP / 4);
    const float4* r1 = T4 + (size_t)i1 * (NP / 4);
    const float4* r2 = T4 + (size_t)i2 * (NP / 4);
    float* o = out + uf;
    #pragma unroll
    for (int c = 0; c < NP / 4; ++c) {
        float4 a = r0[c], b = r1[c], d = r2[c];
        o[(size_t)(4*c + 0) * HW] = w0*a.x + w1*b.x + w2*d.x;
        o[(size_t)(4*c + 1) * HW] = w0*a.y + w1*b.y + w2*d.y;
        o[(size_t)(4*c + 2) * HW] = w0*a.z + w1*b.z + w2*d.z;
        o[(size_t)(4*c + 3) * HW] = w0*a.w + w1*b.w + w2*d.w;
    }
}

// ---------------------------------------------------------------------------
// Fallback path (R0 kernels) in case ws_size < sizeof(T)
// ---------------------------------------------------------------------------

__global__ void copy_even_rows_kernel(const float4* __restrict__ src,
                                      float4* __restrict__ dst) {
    const int per_plane = (H / 2) * (W / 4);
    int t = blockIdx.x * blockDim.x + threadIdx.x;
    if (t >= NP * per_plane) return;
    int p   = t / per_plane;
    int rem = t - p * per_plane;
    int r2  = rem >> 8;
    int c4  = rem & 255;
    int off = p * (HW / 4) + (r2 * 2) * (W / 4) + c4;
    dst[off] = src[off];
}

__global__ void fill_kernel(const float* __restrict__ coded,
                            const int*   __restrict__ idx,
                            const float* __restrict__ dist,
                            const int*   __restrict__ filled_idx,
                            const int*   __restrict__ unfilled_idx,
                            float* __restrict__ out) {
    int u = blockIdx.x * blockDim.x + threadIdx.x;
    if (u >= U) return;
    int i0 = idx[3*u + 0], i1 = idx[3*u + 1], i2 = idx[3*u + 2];
    float w0 = 1.0f / dist[3*u + 0];
    float w1 = 1.0f / dist[3*u + 1];
    float w2 = 1.0f / dist[3*u + 2];
    float inv = 1.0f / (w0 + w1 + w2);
    w0 *= inv; w1 *= inv; w2 *= inv;
    int n0 = filled_idx[2*i0] * W + filled_idx[2*i0 + 1];
    int n1 = filled_idx[2*i1] * W + filled_idx[2*i1 + 1];
    int n2 = filled_idx[2*i2] * W + filled_idx[2*i2 + 1];
    int uf = unfilled_idx[2*u] * W + unfilled_idx[2*u + 1];
    #pragma unroll 4
    for (int p = 0; p < NP; ++p) {
        const float* pl = coded + (size_t)p * HW;
        out[(size_t)p * HW + uf] = w0 * pl[n0] + w1 * pl[n1] + w2 * pl[n2];
    }
}

// ---------------------------------------------------------------------------

extern "C" void kernel_launch(void* const* d_in, const int* in_sizes, int n_in,
                              void* d_out, int out_size, void* d_ws, size_t ws_size,
                              hipStream_t stream) {
    const float* coded        = (const float*)d_in[0];
    const int*   idx          = (const int*)d_in[1];
    const float* dist         = (const float*)d_in[2];
    const int*   filled_idx   = (const int*)d_in[3];
    const int*   unfilled_idx = (const int*)d_in[4];
    float*       out          = (float*)d_out;

    const size_t t_bytes = (size_t)F * NP * sizeof(float);   // 33.5 MB

    if (ws_size >= t_bytes) {
        float4* T4 = (float4*)d_ws;
        build_T_copy_kernel<<<(F + 255) / 256, 256, 0, stream>>>(
            (const float2*)coded, (float2*)out, T4);
        fill_T_kernel<<<(U + 255) / 256, 256, 0, stream>>>(
            idx, dist, T4, out);
    } else {
        const int copy_threads = NP * (H / 2) * (W / 4);
        copy_even_rows_kernel<<<(copy_threads + 255) / 256, 256, 0, stream>>>(
            (const float4*)coded, (float4*)out);
        fill_kernel<<<(U + 255) / 256, 256, 0, stream>>>(
            coded, idx, dist, filled_idx, unfilled_idx, out);
    }
}

// Round 3
// 121.582 us; speedup vs baseline: 8.7435x; 1.1702x over previous
//
#include <hip/hip_runtime.h>

// Problem constants (match reference)
static constexpr int H  = 1024, W = 1024, B = 8, C = 4, K = 3;
static constexpr int HW = H * W;
static constexpr int F  = (H / 2) * (W / 2);   // 262144 filled
static constexpr int U  = HW - F;              // 786432 unfilled
static constexpr int NP = B * C;               // 32 planes

// bf16 helpers (RNE round, manual to keep types simple)
__device__ inline unsigned short f2bf(float f) {
    unsigned u = __float_as_uint(f);
    u += 0x7fffu + ((u >> 16) & 1u);
    return (unsigned short)(u >> 16);
}
__device__ inline float bf_lo(unsigned v) { return __uint_as_float(v << 16); }
__device__ inline float bf_hi(unsigned v) { return __uint_as_float(v & 0xffff0000u); }

// ---------------------------------------------------------------------------
// Fast path: T[f][32] in bf16 — one 64 B cache line per filled pixel.
// ---------------------------------------------------------------------------

// Kernel 1: copy even rows of coded to out (coalesced float2) and build T row
// (32 bf16 = 64 B contiguous, written as 4 uint4... = 16 uints via 4 stores).
__global__ void build_T_copy_kernel(const float2* __restrict__ src2,
                                    float2* __restrict__ dst2,
                                    uint4* __restrict__ T) {
    int f = blockIdx.x * blockDim.x + threadIdx.x;
    if (f >= F) return;
    int r2 = f >> 9;
    int c2 = f & 511;
    int base = r2 * W + c2;                    // float2 index within a plane
    unsigned packed[NP / 2];
    #pragma unroll
    for (int p = 0; p < NP; p += 2) {
        float2 v0 = src2[(size_t)p * (HW / 2) + base];
        float2 v1 = src2[(size_t)(p + 1) * (HW / 2) + base];
        dst2[(size_t)p * (HW / 2) + base] = v0;
        dst2[(size_t)(p + 1) * (HW / 2) + base] = v1;
        packed[p / 2] = (unsigned)f2bf(v0.x) | ((unsigned)f2bf(v1.x) << 16);
    }
    uint4* row = T + (size_t)f * 4;            // 4 × 16 B = 64 B
    #pragma unroll
    for (int c = 0; c < 4; ++c)
        row[c] = make_uint4(packed[4*c], packed[4*c+1], packed[4*c+2], packed[4*c+3]);
}

// Kernel 2: one thread per unfilled pixel u; 3 × 64 B row gathers (12 loads),
// 32 coalesced fp32 stores. uf from the argwhere enumeration closed form.
__global__ void fill_T_kernel(const int*   __restrict__ idx,
                              const float* __restrict__ dist,
                              const uint4* __restrict__ T,
                              float* __restrict__ out) {
    int u = blockIdx.x * blockDim.x + threadIdx.x;
    if (u >= U) return;

    int blk = u / 1536;
    int rem = u - blk * 1536;
    int row, col;
    if (rem < 512) { row = 2 * blk;     col = 2 * rem + 1; }
    else           { row = 2 * blk + 1; col = rem - 512;   }
    int uf = row * W + col;

    int i0 = idx[3*u + 0], i1 = idx[3*u + 1], i2 = idx[3*u + 2];
    float w0 = 1.0f / dist[3*u + 0];
    float w1 = 1.0f / dist[3*u + 1];
    float w2 = 1.0f / dist[3*u + 2];
    float inv = 1.0f / (w0 + w1 + w2);
    w0 *= inv; w1 *= inv; w2 *= inv;

    const uint4* r0 = T + (size_t)i0 * 4;
    const uint4* r1 = T + (size_t)i1 * 4;
    const uint4* r2 = T + (size_t)i2 * 4;
    float* o = out + uf;
    #pragma unroll
    for (int c = 0; c < 4; ++c) {              // each uint4 covers 8 planes
        uint4 a = r0[c], b = r1[c], d = r2[c];
        unsigned av[4] = {a.x, a.y, a.z, a.w};
        unsigned bv[4] = {b.x, b.y, b.z, b.w};
        unsigned dv[4] = {d.x, d.y, d.z, d.w};
        #pragma unroll
        for (int j = 0; j < 4; ++j) {
            int p = c * 8 + j * 2;
            o[(size_t)p * HW]       = w0*bf_lo(av[j]) + w1*bf_lo(bv[j]) + w2*bf_lo(dv[j]);
            o[(size_t)(p+1) * HW]   = w0*bf_hi(av[j]) + w1*bf_hi(bv[j]) + w2*bf_hi(dv[j]);
        }
    }
}

// ---------------------------------------------------------------------------
// Fallback path (R0 kernels) in case ws_size < sizeof(T)
// ---------------------------------------------------------------------------

__global__ void copy_even_rows_kernel(const float4* __restrict__ src,
                                      float4* __restrict__ dst) {
    const int per_plane = (H / 2) * (W / 4);
    int t = blockIdx.x * blockDim.x + threadIdx.x;
    if (t >= NP * per_plane) return;
    int p   = t / per_plane;
    int rem = t - p * per_plane;
    int r2  = rem >> 8;
    int c4  = rem & 255;
    int off = p * (HW / 4) + (r2 * 2) * (W / 4) + c4;
    dst[off] = src[off];
}

__global__ void fill_kernel(const float* __restrict__ coded,
                            const int*   __restrict__ idx,
                            const float* __restrict__ dist,
                            const int*   __restrict__ filled_idx,
                            const int*   __restrict__ unfilled_idx,
                            float* __restrict__ out) {
    int u = blockIdx.x * blockDim.x + threadIdx.x;
    if (u >= U) return;
    int i0 = idx[3*u + 0], i1 = idx[3*u + 1], i2 = idx[3*u + 2];
    float w0 = 1.0f / dist[3*u + 0];
    float w1 = 1.0f / dist[3*u + 1];
    float w2 = 1.0f / dist[3*u + 2];
    float inv = 1.0f / (w0 + w1 + w2);
    w0 *= inv; w1 *= inv; w2 *= inv;
    int n0 = filled_idx[2*i0] * W + filled_idx[2*i0 + 1];
    int n1 = filled_idx[2*i1] * W + filled_idx[2*i1 + 1];
    int n2 = filled_idx[2*i2] * W + filled_idx[2*i2 + 1];
    int uf = unfilled_idx[2*u] * W + unfilled_idx[2*u + 1];
    #pragma unroll 4
    for (int p = 0; p < NP; ++p) {
        const float* pl = coded + (size_t)p * HW;
        out[(size_t)p * HW + uf] = w0 * pl[n0] + w1 * pl[n1] + w2 * pl[n2];
    }
}

// ---------------------------------------------------------------------------

extern "C" void kernel_launch(void* const* d_in, const int* in_sizes, int n_in,
                              void* d_out, int out_size, void* d_ws, size_t ws_size,
                              hipStream_t stream) {
    const float* coded        = (const float*)d_in[0];
    const int*   idx          = (const int*)d_in[1];
    const float* dist         = (const float*)d_in[2];
    const int*   filled_idx   = (const int*)d_in[3];
    const int*   unfilled_idx = (const int*)d_in[4];
    float*       out          = (float*)d_out;

    const size_t t_bytes = (size_t)F * NP * sizeof(unsigned short);   // 16.7 MB

    if (ws_size >= t_bytes) {
        uint4* T = (uint4*)d_ws;
        build_T_copy_kernel<<<(F + 255) / 256, 256, 0, stream>>>(
            (const float2*)coded, (float2*)out, T);
        fill_T_kernel<<<(U + 255) / 256, 256, 0, stream>>>(
            idx, dist, T, out);
    } else {
        const int copy_threads = NP * (H / 2) * (W / 4);
        copy_even_rows_kernel<<<(copy_threads + 255) / 256, 256, 0, stream>>>(
            (const float4*)coded, (float4*)out);
        fill_kernel<<<(U + 255) / 256, 256, 0, stream>>>(
            coded, idx, dist, filled_idx, unfilled_idx, out);
    }
}